// Round 5
// baseline (425.464 us; speedup 1.0000x reference)
//
#include <hip/hip_runtime.h>
#include <hip/hip_bf16.h>
#include <hip/hip_fp16.h>

// TinyTransformerBlock: B=4, S=2048, D=1024, DFF=4096, fp32 in/out.
// R8: algebraic FLOP removal (245 GF): scores = x(wq wk^T)x^T, P-side
// (P(x wv))wo = P(x(wv wo)). Precomputed WqkT/WvoT via gemm_dd.
// R10 8-phase FAILED (78us). R11 XCD swizzle FAILED (+23us). R12 ns2
// consolidation neutral (421us) but exposed the limiter: OccupancyPercent
// 25% = 2 waves/SIMD. True per-wave alloc = 84 VGPR + 64 AGPR acc = 148 ->
// rounds to 256 (64-granular file of 512/SIMD) -> 2 waves/SIMD.
// R13: register diet to <=128 total -> 4 waves/SIMD on ALL GEMMs.
// K-loop reads s0 frags (32 regs), runs s0 MFMAs, REUSES the same regs for
// s1 frags, barrier, ISSUE, s1 MFMAs. __launch_bounds__(256,4) enforces.
// FFN2 moved onto ns2<3> (K-split gemm_f16 was 236 regs — deleted).
// Softmax: LDS-tree reduce (16 barriers) -> wave shuffle reduce (2).

typedef _Float16 f16;
typedef __attribute__((ext_vector_type(8))) _Float16 f16x8;
typedef __attribute__((ext_vector_type(4))) _Float16 f16x4;
typedef __attribute__((ext_vector_type(4))) float f32x4;

#define BM 128
#define BN 128
#define BK 64

__device__ inline void gload16(const void* g, void* l) {
    __builtin_amdgcn_global_load_lds(
        (const __attribute__((address_space(1))) void*)g,
        (__attribute__((address_space(3))) void*)l, 16, 0, 0);
}

// ---------------- R13 no-split kernel (128x128, wave=64x64, z-batch) ------
// EPI: 0 = f16 store, 1 = f16 relu store, 2 = f32 store, 3 = f32 + residual.
// Reg budget: acc 64 (AGPR) + frag 32 + addr ~20 <= 128 -> 4 waves/SIMD.
template<int EPI>
__global__ __launch_bounds__(256, 4)
void gemm_ns2(const f16* __restrict__ A, const f16* __restrict__ Bt,
              const float* __restrict__ Res, void* __restrict__ Cv,
              int K, int lda, int ldb, int ldc,
              long long sA, long long sB, long long sC)
{
    __shared__ f16 Ash[BM * BK];
    __shared__ f16 Bsh[BN * BK];

    const int t = threadIdx.x;
    const int z = blockIdx.z;
    A  += (size_t)z * sA;
    Bt += (size_t)z * sB;

    const int bm0 = blockIdx.x * BM;
    const int bn0 = blockIdx.y * BN;

    const int lane = t & 63;
    const int wid  = t >> 6;
    const int quad = lane >> 4;
    const int m16  = lane & 15;
    const int wm = (wid & 1) * 64;
    const int wn = (wid >> 1) * 64;

    const int r0 = t >> 3;
    const int kc = ((t & 7) ^ (r0 & 7)) * 8;
    const char* gA[4]; const char* gB[4];
    #pragma unroll
    for (int i = 0; i < 4; ++i) {
        gA[i] = (const char*)(A  + (size_t)(bm0 + i * 32 + r0) * lda + kc);
        gB[i] = (const char*)(Bt + (size_t)(bn0 + i * 32 + r0) * ldb + kc);
    }
    char* lA = (char*)Ash + (wid << 10);
    char* lB = (char*)Bsh + (wid << 10);

    f32x4 acc[4][4] = {};

    const int nk = K / BK;
    #define ISSUE(kt) do { const int ko = (kt) * 128;   \
        gload16(gA[0] + ko, lA);                        \
        gload16(gA[1] + ko, lA + 4096);                 \
        gload16(gA[2] + ko, lA + 8192);                 \
        gload16(gA[3] + ko, lA + 12288);                \
        gload16(gB[0] + ko, lB);                        \
        gload16(gB[1] + ko, lB + 4096);                 \
        gload16(gB[2] + ko, lB + 8192);                 \
        gload16(gB[3] + ko, lB + 12288); } while (0)

    const int swz = m16 & 7;
    const int ha0 = ((quad)     ^ swz) * 8;
    const int ha1 = ((4 | quad) ^ swz) * 8;

    ISSUE(0);
    for (int kt = 0; kt < nk; ++kt) {
        __syncthreads();
        f16x8 af[4], bf[4];
        // k-half 0: load frags, consume immediately (regs freed for half 1)
        #pragma unroll
        for (int i = 0; i < 4; ++i) {
            af[i] = *(const f16x8*)&Ash[(wm + i * 16 + m16) * BK + ha0];
            bf[i] = *(const f16x8*)&Bsh[(wn + i * 16 + m16) * BK + ha0];
        }
        #pragma unroll
        for (int i = 0; i < 4; ++i)
            #pragma unroll
            for (int j = 0; j < 4; ++j)
                acc[i][j] = __builtin_amdgcn_mfma_f32_16x16x32_f16(
                                af[i], bf[j], acc[i][j], 0, 0, 0);
        // k-half 1: reuse frag regs; reads must finish before barrier2
        #pragma unroll
        for (int i = 0; i < 4; ++i) {
            af[i] = *(const f16x8*)&Ash[(wm + i * 16 + m16) * BK + ha1];
            bf[i] = *(const f16x8*)&Bsh[(wn + i * 16 + m16) * BK + ha1];
        }
        __syncthreads();
        if (kt + 1 < nk) ISSUE(kt + 1);
        #pragma unroll
        for (int i = 0; i < 4; ++i)
            #pragma unroll
            for (int j = 0; j < 4; ++j)
                acc[i][j] = __builtin_amdgcn_mfma_f32_16x16x32_f16(
                                af[i], bf[j], acc[i][j], 0, 0, 0);
    }
    #undef ISSUE

    if (EPI <= 1) {
        f16* C = (f16*)Cv + (size_t)z * sC;
        #pragma unroll
        for (int i = 0; i < 4; ++i)
            #pragma unroll
            for (int ri = 0; ri < 4; ++ri) {
                const size_t row = (size_t)(bm0 + wm + i * 16 + quad * 4 + ri);
                f16* cp = C + row * ldc + (bn0 + wn + m16);
                #pragma unroll
                for (int j = 0; j < 4; ++j) {
                    float v = acc[i][j][ri];
                    if (EPI == 1) v = fmaxf(v, 0.0f);
                    cp[j * 16] = (f16)v;
                }
            }
    } else {
        float* C = (float*)Cv + (size_t)z * sC;
        #pragma unroll
        for (int i = 0; i < 4; ++i)
            #pragma unroll
            for (int ri = 0; ri < 4; ++ri) {
                const size_t row = (size_t)(bm0 + wm + i * 16 + quad * 4 + ri);
                float* cp = C + row * ldc + (bn0 + wn + m16);
                const float* rp = (EPI == 3)
                    ? Res + row * ldc + (bn0 + wn + m16) : nullptr;
                #pragma unroll
                for (int j = 0; j < 4; ++j) {
                    float v = acc[i][j][ri];
                    if (EPI == 3) v += rp[j * 16];
                    cp[j * 16] = v;
                }
            }
    }
}

// ---------------- small D x D kernel: two 1024^3 products in one launch ---
__global__ __launch_bounds__(256, 2)
void gemm_dd(const f16* __restrict__ A0, const f16* __restrict__ B0, f16* __restrict__ C0,
             const f16* __restrict__ A1, const f16* __restrict__ B1, f16* __restrict__ C1)
{
    const int LD = 1024;
    __shared__ char smem[32 * 1024];
    f16* Ash = (f16*)smem;             // 16 KB: 64 rows x 128 k
    f16* Bsh = (f16*)(smem + 16384);   // 16 KB
    float* xred = (float*)smem;        // reduce regions alias staging

    const int t = threadIdx.x;
    const int z = blockIdx.z;
    const f16* A = z ? A1 : A0;
    const f16* B = z ? B1 : B0;
    f16* C = z ? C1 : C0;

    const int bm0 = blockIdx.x * 64;
    const int bn0 = blockIdx.y * 64;

    const int lane = t & 63;
    const int wid  = t >> 6;            // wave = k-quarter ks
    const int quad = lane >> 4;
    const int m16  = lane & 15;

    const int rr = t >> 4;              // 0..15
    const int kc = ((t & 15) ^ (rr & 15)) * 8;
    const char* gA[4]; const char* gB[4];
    #pragma unroll
    for (int i = 0; i < 4; ++i) {
        gA[i] = (const char*)(A + (size_t)(bm0 + i * 16 + rr) * LD + kc);
        gB[i] = (const char*)(B + (size_t)(bn0 + i * 16 + rr) * LD + kc);
    }
    char* lA = (char*)Ash + (wid << 10);
    char* lB = (char*)Bsh + (wid << 10);

    f32x4 acc[4][4] = {};

    #define ISSUE(kt) do { const int ko = (kt) * 256;   \
        gload16(gA[0] + ko, lA);                        \
        gload16(gA[1] + ko, lA + 4096);                 \
        gload16(gA[2] + ko, lA + 8192);                 \
        gload16(gA[3] + ko, lA + 12288);                \
        gload16(gB[0] + ko, lB);                        \
        gload16(gB[1] + ko, lB + 4096);                 \
        gload16(gB[2] + ko, lB + 8192);                 \
        gload16(gB[3] + ko, lB + 12288); } while (0)

    const int sl = ((wid * 4 + quad) ^ m16) * 8;   // swizzled slot (16 slots)

    ISSUE(0);
    for (int kt = 0; kt < 8; ++kt) {     // K = 1024, BK = 128
        __syncthreads();
        f16x8 af[4], bf[4];
        #pragma unroll
        for (int i = 0; i < 4; ++i) {
            af[i] = *(const f16x8*)&Ash[(i * 16 + m16) * 128 + sl];
            bf[i] = *(const f16x8*)&Bsh[(i * 16 + m16) * 128 + sl];
        }
        __syncthreads();
        if (kt + 1 < 8) ISSUE(kt + 1);
        #pragma unroll
        for (int i = 0; i < 4; ++i)
            #pragma unroll
            for (int j = 0; j < 4; ++j)
                acc[i][j] = __builtin_amdgcn_mfma_f32_16x16x32_f16(
                                af[i], bf[j], acc[i][j], 0, 0, 0);
    }
    #undef ISSUE

    #define XIDX(row, col) ((row) * 64 + ((col) ^ (((row) & 4) << 2)))
    #define WR(base) do {                                                       \
        _Pragma("unroll")                                                       \
        for (int i = 0; i < 4; ++i)                                             \
            _Pragma("unroll")                                                   \
            for (int j = 0; j < 4; ++j)                                         \
                _Pragma("unroll")                                               \
                for (int ri = 0; ri < 4; ++ri)                                  \
                    (base)[XIDX(i * 16 + quad * 4 + ri, j * 16 + m16)] = acc[i][j][ri]; \
        } while (0)
    #define RD(base) do {                                                       \
        _Pragma("unroll")                                                       \
        for (int i = 0; i < 4; ++i)                                             \
            _Pragma("unroll")                                                   \
            for (int j = 0; j < 4; ++j)                                         \
                _Pragma("unroll")                                               \
                for (int ri = 0; ri < 4; ++ri)                                  \
                    acc[i][j][ri] += (base)[XIDX(i * 16 + quad * 4 + ri, j * 16 + m16)]; \
        } while (0)

    __syncthreads();
    if (wid == 2) WR(xred);
    if (wid == 3) WR(xred + 4096);
    __syncthreads();
    if (wid == 0) RD(xred);
    if (wid == 1) RD(xred + 4096);
    __syncthreads();
    if (wid == 1) WR(xred);
    __syncthreads();
    if (wid == 0) {
        RD(xred);
        #pragma unroll
        for (int i = 0; i < 4; ++i)
            #pragma unroll
            for (int ri = 0; ri < 4; ++ri) {
                const size_t row = (size_t)(bm0 + i * 16 + quad * 4 + ri);
                f16* cp = C + row * LD + (bn0 + m16);
                #pragma unroll
                for (int j = 0; j < 4; ++j)
                    cp[j * 16] = (f16)acc[i][j][ri];
            }
    }
    #undef WR
    #undef RD
    #undef XIDX
}

// fused fp32 [R][C] -> fp16 [C][R] for wo/w1/w2 in one launch (z = 0..2)
__global__ __launch_bounds__(256)
void transpose_all(const float* __restrict__ wo, const float* __restrict__ w1,
                   const float* __restrict__ w2,
                   f16* __restrict__ woT, f16* __restrict__ w1T,
                   f16* __restrict__ w2T)
{
    const int z = blockIdx.z;
    const float* in; f16* out; int R, C, gx, gy;
    if (z == 0)      { in = wo; out = woT; R = 1024; C = 1024; gx = 16; gy = 16; }
    else if (z == 1) { in = w1; out = w1T; R = 1024; C = 4096; gx = 64; gy = 16; }
    else             { in = w2; out = w2T; R = 4096; C = 1024; gx = 16; gy = 64; }
    if (blockIdx.x >= (unsigned)gx || blockIdx.y >= (unsigned)gy) return;

    __shared__ float tile[64][65];
    const int c0 = blockIdx.x * 64, r0 = blockIdx.y * 64;
    const int tc = threadIdx.x & 63, tr = threadIdx.x >> 6;
    #pragma unroll
    for (int i = 0; i < 16; ++i)
        tile[tr + i * 4][tc] = in[(size_t)(r0 + tr + i * 4) * C + c0 + tc];
    __syncthreads();
    #pragma unroll
    for (int i = 0; i < 16; ++i)
        out[(size_t)(c0 + tr + i * 4) * R + r0 + tc] = (f16)tile[tc][tr + i * 4];
}

// fused fp32->f16 casts: z=0: x (8192 blocks), z=1..3: wq/wk/wv (1024 each)
__global__ __launch_bounds__(256)
void cast_all(const float* __restrict__ x, const float* __restrict__ wq,
              const float* __restrict__ wk, const float* __restrict__ wv,
              f16* __restrict__ xh, f16* __restrict__ wqh,
              f16* __restrict__ wkh, f16* __restrict__ wvh)
{
    const int z = blockIdx.z;
    const float* in; f16* out; unsigned nblk;
    if (z == 0)      { in = x;  out = xh;  nblk = 8192; }
    else if (z == 1) { in = wq; out = wqh; nblk = 1024; }
    else if (z == 2) { in = wk; out = wkh; nblk = 1024; }
    else             { in = wv; out = wvh; nblk = 1024; }
    if (blockIdx.x >= nblk) return;
    const size_t i = ((size_t)blockIdx.x * 256 + threadIdx.x) * 4;
    float4 v = *(const float4*)(in + i);
    f16x4 o; o.x = (f16)v.x; o.y = (f16)v.y; o.z = (f16)v.z; o.w = (f16)v.w;
    *(f16x4*)(out + i) = o;
}

// in-place row softmax: reads fp32 row (2048), writes f16 probs into the
// first half of the same row (row pitch 4096 f16). Wave shuffle reduce.
__global__ __launch_bounds__(256)
void softmax_f16(float* __restrict__ S)
{
    __shared__ float redm[4], reds[4];
    float* p = S + (size_t)blockIdx.x * 2048;
    f16* q = (f16*)p;
    const int t = threadIdx.x;
    const int lane = t & 63, wid = t >> 6;

    float4 u0 = *(const float4*)(p + t * 4);
    float4 u1 = *(const float4*)(p + 1024 + t * 4);

    float m = fmaxf(fmaxf(fmaxf(u0.x, u0.y), fmaxf(u0.z, u0.w)),
                    fmaxf(fmaxf(u1.x, u1.y), fmaxf(u1.z, u1.w)));
    #pragma unroll
    for (int off = 32; off > 0; off >>= 1)
        m = fmaxf(m, __shfl_xor(m, off));
    if (lane == 0) redm[wid] = m;
    __syncthreads();
    const float rowmax = fmaxf(fmaxf(redm[0], redm[1]),
                               fmaxf(redm[2], redm[3]));

    u0.x = __expf(u0.x - rowmax); u0.y = __expf(u0.y - rowmax);
    u0.z = __expf(u0.z - rowmax); u0.w = __expf(u0.w - rowmax);
    u1.x = __expf(u1.x - rowmax); u1.y = __expf(u1.y - rowmax);
    u1.z = __expf(u1.z - rowmax); u1.w = __expf(u1.w - rowmax);

    float s = (u0.x + u0.y + u0.z + u0.w) + (u1.x + u1.y + u1.z + u1.w);
    #pragma unroll
    for (int off = 32; off > 0; off >>= 1)
        s += __shfl_xor(s, off);
    if (lane == 0) reds[wid] = s;
    __syncthreads();   // also orders all row loads before the in-place write
    const float inv = 1.0f / (reds[0] + reds[1] + reds[2] + reds[3]);

    f16x4 o0, o1;
    o0.x = (f16)(u0.x * inv); o0.y = (f16)(u0.y * inv);
    o0.z = (f16)(u0.z * inv); o0.w = (f16)(u0.w * inv);
    o1.x = (f16)(u1.x * inv); o1.y = (f16)(u1.y * inv);
    o1.z = (f16)(u1.z * inv); o1.w = (f16)(u1.w * inv);
    *(f16x4*)(q + t * 4)        = o0;
    *(f16x4*)(q + 1024 + t * 4) = o1;
}

extern "C" void kernel_launch(void* const* d_in, const int* in_sizes, int n_in,
                              void* d_out, int out_size, void* d_ws, size_t ws_size,
                              hipStream_t stream)
{
    const float* x  = (const float*)d_in[0];
    const float* wq = (const float*)d_in[1];
    const float* wk = (const float*)d_in[2];
    const float* wv = (const float*)d_in[3];
    const float* wo = (const float*)d_in[4];
    const float* w1 = (const float*)d_in[5];
    const float* w2 = (const float*)d_in[6];
    float* out = (float*)d_out;

    const int S = 2048, D = 1024, DFF = 4096, Bb = 4;
    const int NTOK = Bb * S;  // 8192
    const size_t M1 = 1024 * 1024;

    // workspace (f16 units); peak 140 MB
    f16* W    = (f16*)d_ws;
    f16* xh   = W;                      // [0, 8M)
    f16* wqh  = W + 8 * M1;             // 1M each
    f16* wkh  = W + 9 * M1;
    f16* wvh  = W + 10 * M1;
    f16* woT  = W + 11 * M1;
    f16* w1T  = W + 12 * M1;            // 4M
    f16* w2T  = W + 16 * M1;            // 4M
    f16* wqkT = W + 20 * M1;            // 1M  (= wk @ wq^T)
    f16* wvoT = W + 21 * M1;            // 1M  (= (wv @ wo)^T)
    f16* qp   = W + 22 * M1;            // 8M  (q' = x @ Wqk)
    f16* vwT  = W + 30 * M1;            // 8M  ([1024][8192] = (x @ Wvo)^T)
    float* sb = (float*)(W + 38 * M1);  // 16M fp32 scores (64 MB)
    f16* ph   = (f16*)sb;               // probs in-place, row pitch 4096 f16
    f16* pj   = xh;                     // P @ vw  overwrites xh (dead)
    f16* hd   = qp;                     // hidden overwrites qp+vwT+sb regions

    dim3 blk(256);

    // fused casts / transposes, then weight products
    cast_all<<<dim3(NTOK * D / 1024, 1, 4), blk, 0, stream>>>(
        x, wq, wk, wv, xh, wqh, wkh, wvh);
    transpose_all<<<dim3(64, 64, 3), blk, 0, stream>>>(
        wo, w1, w2, woT, w1T, w2T);
    // wqkT = wk @ wq^T ; wvoT = NT(woT, wvh) = (wv @ wo)^T
    gemm_dd<<<dim3(16, 16, 2), blk, 0, stream>>>(
        wkh, wqh, wqkT, woT, wvh, wvoT);

    // q' = xh @ wqkT'   [8192][1024]
    gemm_ns2<0><<<dim3(NTOK / BM, D / BN, 1), blk, 0, stream>>>(
        xh, wqkT, nullptr, qp, D, D, D, D, 0, 0, 0);
    // vwT = wvoT @ xh'  [1024][8192]
    gemm_ns2<0><<<dim3(D / BM, NTOK / BN, 1), blk, 0, stream>>>(
        wvoT, xh, nullptr, vwT, D, D, D, NTOK, 0, 0, 0);

    // scores[b] = q'_b @ xh_b'   fp32 [2048][2048] x4
    gemm_ns2<2><<<dim3(S / BM, S / BN, Bb), blk, 0, stream>>>(
        qp, xh, nullptr, sb, D, D, D, S,
        (long long)S * D, (long long)S * D, (long long)S * S);

    // softmax -> f16 probs in place (row pitch 4096)
    softmax_f16<<<dim3(NTOK), blk, 0, stream>>>(sb);

    // pj[b] = P_b @ (vwT[:, b-slice])'   [2048][1024] x4
    gemm_ns2<0><<<dim3(S / BM, D / BN, Bb), blk, 0, stream>>>(
        ph, vwT, nullptr, pj, S, 4096, NTOK, D,
        (long long)S * 4096, (long long)S, (long long)S * D);

    // hidden = relu(pj @ w1T')   [8192][4096]
    gemm_ns2<1><<<dim3(NTOK / BM, DFF / BN, 1), blk, 0, stream>>>(
        pj, w1T, nullptr, hd, D, D, D, DFF, 0, 0, 0);

    // out = hd @ w2T' + x   fp32 [8192][1024]
    gemm_ns2<3><<<dim3(NTOK / BM, D / BN, 1), blk, 0, stream>>>(
        hd, w2T, x, out, DFF, DFF, DFF, D, 0, 0, 0);
}

// Round 7
// 411.456 us; speedup vs baseline: 1.0340x; 1.0340x over previous
//
#include <hip/hip_runtime.h>
#include <hip/hip_bf16.h>
#include <hip/hip_fp16.h>

// TinyTransformerBlock: B=4, S=2048, D=1024, DFF=4096, fp32 in/out.
// R8: algebraic FLOP removal (245 GF). R10 8-phase FAILED; R11 XCD swizzle
// FAILED; R13 reg-diet neutral; R14 micro-wins had a workspace ALIASING BUG:
// pj was placed inside the live sb (scores) region -> PV overwrote probs
// mid-read (absmax 19.25). R15 = R14 with a corrected, non-overlapping map:
//   xh 0..8M | weights 8..22M | qp 22..30M | vwT 30..38M | sb 38..70M
//   pj = qp slot (dead after scores) | hd = sb slot (dead after PV)
// Peak 70M f16 = 140 MB (the proven R1-R13 footprint). xh stays live to
// serve as FFN2's f16 residual (-16 MB fetch, adds <=2.2e-3 abs error).

typedef _Float16 f16;
typedef __attribute__((ext_vector_type(8))) _Float16 f16x8;
typedef __attribute__((ext_vector_type(4))) _Float16 f16x4;
typedef __attribute__((ext_vector_type(4))) float f32x4;

#define BM 128
#define BN 128
#define BK 64

__device__ inline void gload16(const void* g, void* l) {
    __builtin_amdgcn_global_load_lds(
        (const __attribute__((address_space(1))) void*)g,
        (__attribute__((address_space(3))) void*)l, 16, 0, 0);
}

// ---------------- K-split kernel (128x128) — FFN2 (K=4096) ----------------
// EPI 3 = f32 store + f16 residual add. 8 acc tiles, 2-way wave K-split,
// LDS cross-reduce. Best measured for K=4096 (69.3 us R1).
template<int EPI>
__global__ __launch_bounds__(256, 2)
void gemm_f16(const f16* __restrict__ A, const f16* __restrict__ Bt,
              const f16* __restrict__ Res, float* __restrict__ C,
              int K, int lda, int ldb, int ldc)
{
    __shared__ char smem[32 * 1024];
    f16* Ash = (f16*)smem;
    f16* Bsh = (f16*)(smem + 16384);
    float* xbuf = (float*)smem;

    const int t = threadIdx.x;
    const int bm0 = blockIdx.x * BM;
    const int bn0 = blockIdx.y * BN;

    const int lane = t & 63;
    const int wid  = t >> 6;
    const int quad = lane >> 4;
    const int m16  = lane & 15;
    const int ks   = wid & 1;
    const int wn64 = (wid >> 1) * 64;

    const int r0 = t >> 3;
    const int kc = ((t & 7) ^ (r0 & 7)) * 8;
    const char* gA[4]; const char* gB[4];
    #pragma unroll
    for (int i = 0; i < 4; ++i) {
        gA[i] = (const char*)(A  + (size_t)(bm0 + i * 32 + r0) * lda + kc);
        gB[i] = (const char*)(Bt + (size_t)(bn0 + i * 32 + r0) * ldb + kc);
    }
    char* lA = (char*)Ash + (wid << 10);
    char* lB = (char*)Bsh + (wid << 10);

    f32x4 acc[8][4] = {};

    const int nk = K / BK;
    #define ISSUE(kt) do { const int ko = (kt) * 128;   \
        gload16(gA[0] + ko, lA);                        \
        gload16(gA[1] + ko, lA + 4096);                 \
        gload16(gA[2] + ko, lA + 8192);                 \
        gload16(gA[3] + ko, lA + 12288);                \
        gload16(gB[0] + ko, lB);                        \
        gload16(gB[1] + ko, lB + 4096);                 \
        gload16(gB[2] + ko, lB + 8192);                 \
        gload16(gB[3] + ko, lB + 12288); } while (0)

    const int swz = m16 & 7;
    const int ha  = ((ks * 4 + quad) ^ swz) * 8;

    ISSUE(0);
    for (int kt = 0; kt < nk; ++kt) {
        __syncthreads();
        f16x8 af[8], bf[4];
        #pragma unroll
        for (int i = 0; i < 8; ++i)
            af[i] = *(const f16x8*)&Ash[(i * 16 + m16) * BK + ha];
        #pragma unroll
        for (int j = 0; j < 4; ++j)
            bf[j] = *(const f16x8*)&Bsh[(wn64 + j * 16 + m16) * BK + ha];
        __syncthreads();
        if (kt + 1 < nk) ISSUE(kt + 1);
        #pragma unroll
        for (int i = 0; i < 8; ++i)
            #pragma unroll
            for (int j = 0; j < 4; ++j)
                acc[i][j] = __builtin_amdgcn_mfma_f32_16x16x32_f16(
                                af[i], bf[j], acc[i][j], 0, 0, 0);
    }
    #undef ISSUE

    float* xb = xbuf + (wid >> 1) * 4096;
    #define XIDX(row, col) ((row) * 64 + ((col) ^ (((row) & 4) << 2)))
    if (ks == 1) {
        #pragma unroll
        for (int i = 0; i < 4; ++i)
            #pragma unroll
            for (int j = 0; j < 4; ++j)
                #pragma unroll
                for (int ri = 0; ri < 4; ++ri)
                    xb[XIDX(i * 16 + quad * 4 + ri, j * 16 + m16)] = acc[i][j][ri];
    }
    __syncthreads();
    if (ks == 0) {
        #pragma unroll
        for (int i = 0; i < 4; ++i)
            #pragma unroll
            for (int j = 0; j < 4; ++j)
                #pragma unroll
                for (int ri = 0; ri < 4; ++ri)
                    acc[i][j][ri] += xb[XIDX(i * 16 + quad * 4 + ri, j * 16 + m16)];
    }
    __syncthreads();
    if (ks == 0) {
        #pragma unroll
        for (int i = 0; i < 4; ++i)
            #pragma unroll
            for (int j = 0; j < 4; ++j)
                #pragma unroll
                for (int ri = 0; ri < 4; ++ri)
                    xb[XIDX(i * 16 + quad * 4 + ri, j * 16 + m16)] = acc[i + 4][j][ri];
    }
    __syncthreads();
    if (ks == 1) {
        #pragma unroll
        for (int i = 0; i < 4; ++i)
            #pragma unroll
            for (int j = 0; j < 4; ++j)
                #pragma unroll
                for (int ri = 0; ri < 4; ++ri)
                    acc[i + 4][j][ri] += xb[XIDX(i * 16 + quad * 4 + ri, j * 16 + m16)];
    }
    #undef XIDX

    #define STORE_TILE(IB, RB)                                                  \
        do {                                                                    \
            _Pragma("unroll")                                                   \
            for (int i = 0; i < 4; ++i)                                         \
                _Pragma("unroll")                                               \
                for (int ri = 0; ri < 4; ++ri) {                                \
                    const size_t row = (size_t)(bm0 + (RB) + i * 16 + quad * 4 + ri); \
                    float* cp = C + row * ldc + (bn0 + wn64 + m16);             \
                    const f16* rp = Res + row * ldc + (bn0 + wn64 + m16);       \
                    _Pragma("unroll")                                           \
                    for (int j = 0; j < 4; ++j) {                               \
                        float v = acc[(IB) + i][j][ri];                         \
                        if (EPI == 3) v += (float)rp[j * 16];                   \
                        cp[j * 16] = v;                                         \
                    }                                                           \
                }                                                               \
        } while (0)

    if (ks == 0) STORE_TILE(0, 0);
    else         STORE_TILE(4, 64);
    #undef STORE_TILE
}

// ---------------- no-split kernel (128x128, wave=64x64, z-batch) ----------
// EPI: 0 = f16 store, 1 = f16 relu store, 2 = f32 store.  (R12 form.)
template<int EPI>
__global__ __launch_bounds__(256, 2)
void gemm_ns2(const f16* __restrict__ A, const f16* __restrict__ Bt,
              void* __restrict__ Cv,
              int K, int lda, int ldb, int ldc,
              long long sA, long long sB, long long sC)
{
    __shared__ f16 Ash[BM * BK];
    __shared__ f16 Bsh[BN * BK];

    const int t = threadIdx.x;
    const int z = blockIdx.z;
    A  += (size_t)z * sA;
    Bt += (size_t)z * sB;

    const int bm0 = blockIdx.x * BM;
    const int bn0 = blockIdx.y * BN;

    const int lane = t & 63;
    const int wid  = t >> 6;
    const int quad = lane >> 4;
    const int m16  = lane & 15;
    const int wm = (wid & 1) * 64;
    const int wn = (wid >> 1) * 64;

    const int r0 = t >> 3;
    const int kc = ((t & 7) ^ (r0 & 7)) * 8;
    const char* gA[4]; const char* gB[4];
    #pragma unroll
    for (int i = 0; i < 4; ++i) {
        gA[i] = (const char*)(A  + (size_t)(bm0 + i * 32 + r0) * lda + kc);
        gB[i] = (const char*)(Bt + (size_t)(bn0 + i * 32 + r0) * ldb + kc);
    }
    char* lA = (char*)Ash + (wid << 10);
    char* lB = (char*)Bsh + (wid << 10);

    f32x4 acc[4][4] = {};

    const int nk = K / BK;
    #define ISSUE(kt) do { const int ko = (kt) * 128;   \
        gload16(gA[0] + ko, lA);                        \
        gload16(gA[1] + ko, lA + 4096);                 \
        gload16(gA[2] + ko, lA + 8192);                 \
        gload16(gA[3] + ko, lA + 12288);                \
        gload16(gB[0] + ko, lB);                        \
        gload16(gB[1] + ko, lB + 4096);                 \
        gload16(gB[2] + ko, lB + 8192);                 \
        gload16(gB[3] + ko, lB + 12288); } while (0)

    const int swz = m16 & 7;

    ISSUE(0);
    for (int kt = 0; kt < nk; ++kt) {
        __syncthreads();
        f16x8 af[2][4], bf[2][4];
        #pragma unroll
        for (int s = 0; s < 2; ++s) {
            const int ha = (((s << 2) | quad) ^ swz) * 8;
            #pragma unroll
            for (int i = 0; i < 4; ++i) {
                af[s][i] = *(const f16x8*)&Ash[(wm + i * 16 + m16) * BK + ha];
                bf[s][i] = *(const f16x8*)&Bsh[(wn + i * 16 + m16) * BK + ha];
            }
        }
        __syncthreads();
        if (kt + 1 < nk) ISSUE(kt + 1);
        #pragma unroll
        for (int s = 0; s < 2; ++s)
            #pragma unroll
            for (int i = 0; i < 4; ++i)
                #pragma unroll
                for (int j = 0; j < 4; ++j)
                    acc[i][j] = __builtin_amdgcn_mfma_f32_16x16x32_f16(
                                    af[s][i], bf[s][j], acc[i][j], 0, 0, 0);
    }
    #undef ISSUE

    if (EPI <= 1) {
        f16* C = (f16*)Cv + (size_t)z * sC;
        #pragma unroll
        for (int i = 0; i < 4; ++i)
            #pragma unroll
            for (int ri = 0; ri < 4; ++ri) {
                const size_t row = (size_t)(bm0 + wm + i * 16 + quad * 4 + ri);
                f16* cp = C + row * ldc + (bn0 + wn + m16);
                #pragma unroll
                for (int j = 0; j < 4; ++j) {
                    float v = acc[i][j][ri];
                    if (EPI == 1) v = fmaxf(v, 0.0f);
                    cp[j * 16] = (f16)v;
                }
            }
    } else {
        float* C = (float*)Cv + (size_t)z * sC;
        #pragma unroll
        for (int i = 0; i < 4; ++i)
            #pragma unroll
            for (int ri = 0; ri < 4; ++ri) {
                const size_t row = (size_t)(bm0 + wm + i * 16 + quad * 4 + ri);
                float* cp = C + row * ldc + (bn0 + wn + m16);
                #pragma unroll
                for (int j = 0; j < 4; ++j)
                    cp[j * 16] = acc[i][j][ri];
            }
    }
}

// ---------------- merged qp + vwT launch (z role-swap, K=1024) ------------
// z=0: qp[8192][1024] = xh @ wqkT^T   (bx = M blocks 64, by = N blocks 8)
// z=1: vwT[1024][8192] = wvoT @ xh^T  (by = M blocks 8,  bx = N blocks 64)
__global__ __launch_bounds__(256, 2)
void gemm_qv(const f16* __restrict__ xh, const f16* __restrict__ wqkT,
             const f16* __restrict__ wvoT,
             f16* __restrict__ qp, f16* __restrict__ vwT)
{
    __shared__ f16 Ash[BM * BK];
    __shared__ f16 Bsh[BN * BK];

    const int t = threadIdx.x;
    const int z = blockIdx.z;
    const f16* A  = z ? wvoT : xh;
    const f16* Bt = z ? xh   : wqkT;
    f16* C        = z ? vwT  : qp;
    const int lda = 1024, ldb = 1024;
    const int ldc = z ? 8192 : 1024;
    const int bm0 = (z ? blockIdx.y : blockIdx.x) * BM;
    const int bn0 = (z ? blockIdx.x : blockIdx.y) * BN;

    const int lane = t & 63;
    const int wid  = t >> 6;
    const int quad = lane >> 4;
    const int m16  = lane & 15;
    const int wm = (wid & 1) * 64;
    const int wn = (wid >> 1) * 64;

    const int r0 = t >> 3;
    const int kc = ((t & 7) ^ (r0 & 7)) * 8;
    const char* gA[4]; const char* gB[4];
    #pragma unroll
    for (int i = 0; i < 4; ++i) {
        gA[i] = (const char*)(A  + (size_t)(bm0 + i * 32 + r0) * lda + kc);
        gB[i] = (const char*)(Bt + (size_t)(bn0 + i * 32 + r0) * ldb + kc);
    }
    char* lA = (char*)Ash + (wid << 10);
    char* lB = (char*)Bsh + (wid << 10);

    f32x4 acc[4][4] = {};

    #define ISSUE(kt) do { const int ko = (kt) * 128;   \
        gload16(gA[0] + ko, lA);                        \
        gload16(gA[1] + ko, lA + 4096);                 \
        gload16(gA[2] + ko, lA + 8192);                 \
        gload16(gA[3] + ko, lA + 12288);                \
        gload16(gB[0] + ko, lB);                        \
        gload16(gB[1] + ko, lB + 4096);                 \
        gload16(gB[2] + ko, lB + 8192);                 \
        gload16(gB[3] + ko, lB + 12288); } while (0)

    const int swz = m16 & 7;

    ISSUE(0);
    for (int kt = 0; kt < 16; ++kt) {    // K = 1024
        __syncthreads();
        f16x8 af[2][4], bf[2][4];
        #pragma unroll
        for (int s = 0; s < 2; ++s) {
            const int ha = (((s << 2) | quad) ^ swz) * 8;
            #pragma unroll
            for (int i = 0; i < 4; ++i) {
                af[s][i] = *(const f16x8*)&Ash[(wm + i * 16 + m16) * BK + ha];
                bf[s][i] = *(const f16x8*)&Bsh[(wn + i * 16 + m16) * BK + ha];
            }
        }
        __syncthreads();
        if (kt + 1 < 16) ISSUE(kt + 1);
        #pragma unroll
        for (int s = 0; s < 2; ++s)
            #pragma unroll
            for (int i = 0; i < 4; ++i)
                #pragma unroll
                for (int j = 0; j < 4; ++j)
                    acc[i][j] = __builtin_amdgcn_mfma_f32_16x16x32_f16(
                                    af[s][i], bf[s][j], acc[i][j], 0, 0, 0);
    }
    #undef ISSUE

    #pragma unroll
    for (int i = 0; i < 4; ++i)
        #pragma unroll
        for (int ri = 0; ri < 4; ++ri) {
            const size_t row = (size_t)(bm0 + wm + i * 16 + quad * 4 + ri);
            f16* cp = C + row * ldc + (bn0 + wn + m16);
            #pragma unroll
            for (int j = 0; j < 4; ++j)
                cp[j * 16] = (f16)acc[i][j][ri];
        }
}

// ---------------- small D x D kernel: two 1024^3 products in one launch ---
__global__ __launch_bounds__(256, 2)
void gemm_dd(const f16* __restrict__ A0, const f16* __restrict__ B0, f16* __restrict__ C0,
             const f16* __restrict__ A1, const f16* __restrict__ B1, f16* __restrict__ C1)
{
    const int LD = 1024;
    __shared__ char smem[32 * 1024];
    f16* Ash = (f16*)smem;             // 16 KB: 64 rows x 128 k
    f16* Bsh = (f16*)(smem + 16384);   // 16 KB
    float* xred = (float*)smem;        // reduce regions alias staging

    const int t = threadIdx.x;
    const int z = blockIdx.z;
    const f16* A = z ? A1 : A0;
    const f16* B = z ? B1 : B0;
    f16* C = z ? C1 : C0;

    const int bm0 = blockIdx.x * 64;
    const int bn0 = blockIdx.y * 64;

    const int lane = t & 63;
    const int wid  = t >> 6;            // wave = k-quarter ks
    const int quad = lane >> 4;
    const int m16  = lane & 15;

    const int rr = t >> 4;              // 0..15
    const int kc = ((t & 15) ^ (rr & 15)) * 8;
    const char* gA[4]; const char* gB[4];
    #pragma unroll
    for (int i = 0; i < 4; ++i) {
        gA[i] = (const char*)(A + (size_t)(bm0 + i * 16 + rr) * LD + kc);
        gB[i] = (const char*)(B + (size_t)(bn0 + i * 16 + rr) * LD + kc);
    }
    char* lA = (char*)Ash + (wid << 10);
    char* lB = (char*)Bsh + (wid << 10);

    f32x4 acc[4][4] = {};

    #define ISSUE(kt) do { const int ko = (kt) * 256;   \
        gload16(gA[0] + ko, lA);                        \
        gload16(gA[1] + ko, lA + 4096);                 \
        gload16(gA[2] + ko, lA + 8192);                 \
        gload16(gA[3] + ko, lA + 12288);                \
        gload16(gB[0] + ko, lB);                        \
        gload16(gB[1] + ko, lB + 4096);                 \
        gload16(gB[2] + ko, lB + 8192);                 \
        gload16(gB[3] + ko, lB + 12288); } while (0)

    const int sl = ((wid * 4 + quad) ^ m16) * 8;   // swizzled slot (16 slots)

    ISSUE(0);
    for (int kt = 0; kt < 8; ++kt) {     // K = 1024, BK = 128
        __syncthreads();
        f16x8 af[4], bf[4];
        #pragma unroll
        for (int i = 0; i < 4; ++i) {
            af[i] = *(const f16x8*)&Ash[(i * 16 + m16) * 128 + sl];
            bf[i] = *(const f16x8*)&Bsh[(i * 16 + m16) * 128 + sl];
        }
        __syncthreads();
        if (kt + 1 < 8) ISSUE(kt + 1);
        #pragma unroll
        for (int i = 0; i < 4; ++i)
            #pragma unroll
            for (int j = 0; j < 4; ++j)
                acc[i][j] = __builtin_amdgcn_mfma_f32_16x16x32_f16(
                                af[i], bf[j], acc[i][j], 0, 0, 0);
    }
    #undef ISSUE

    #define XIDX(row, col) ((row) * 64 + ((col) ^ (((row) & 4) << 2)))
    #define WR(base) do {                                                       \
        _Pragma("unroll")                                                       \
        for (int i = 0; i < 4; ++i)                                             \
            _Pragma("unroll")                                                   \
            for (int j = 0; j < 4; ++j)                                         \
                _Pragma("unroll")                                               \
                for (int ri = 0; ri < 4; ++ri)                                  \
                    (base)[XIDX(i * 16 + quad * 4 + ri, j * 16 + m16)] = acc[i][j][ri]; \
        } while (0)
    #define RD(base) do {                                                       \
        _Pragma("unroll")                                                       \
        for (int i = 0; i < 4; ++i)                                             \
            _Pragma("unroll")                                                   \
            for (int j = 0; j < 4; ++j)                                         \
                _Pragma("unroll")                                               \
                for (int ri = 0; ri < 4; ++ri)                                  \
                    acc[i][j][ri] += (base)[XIDX(i * 16 + quad * 4 + ri, j * 16 + m16)]; \
        } while (0)

    __syncthreads();
    if (wid == 2) WR(xred);
    if (wid == 3) WR(xred + 4096);
    __syncthreads();
    if (wid == 0) RD(xred);
    if (wid == 1) RD(xred + 4096);
    __syncthreads();
    if (wid == 1) WR(xred);
    __syncthreads();
    if (wid == 0) {
        RD(xred);
        #pragma unroll
        for (int i = 0; i < 4; ++i)
            #pragma unroll
            for (int ri = 0; ri < 4; ++ri) {
                const size_t row = (size_t)(bm0 + i * 16 + quad * 4 + ri);
                f16* cp = C + row * LD + (bn0 + m16);
                #pragma unroll
                for (int j = 0; j < 4; ++j)
                    cp[j * 16] = (f16)acc[i][j][ri];
            }
    }
    #undef WR
    #undef RD
    #undef XIDX
}

// fused fp32 [R][C] -> fp16 [C][R] for wo/w1/w2 in one launch (z = 0..2)
__global__ __launch_bounds__(256)
void transpose_all(const float* __restrict__ wo, const float* __restrict__ w1,
                   const float* __restrict__ w2,
                   f16* __restrict__ woT, f16* __restrict__ w1T,
                   f16* __restrict__ w2T)
{
    const int z = blockIdx.z;
    const float* in; f16* out; int R, C, gx, gy;
    if (z == 0)      { in = wo; out = woT; R = 1024; C = 1024; gx = 16; gy = 16; }
    else if (z == 1) { in = w1; out = w1T; R = 1024; C = 4096; gx = 64; gy = 16; }
    else             { in = w2; out = w2T; R = 4096; C = 1024; gx = 16; gy = 64; }
    if (blockIdx.x >= (unsigned)gx || blockIdx.y >= (unsigned)gy) return;

    __shared__ float tile[64][65];
    const int c0 = blockIdx.x * 64, r0 = blockIdx.y * 64;
    const int tc = threadIdx.x & 63, tr = threadIdx.x >> 6;
    #pragma unroll
    for (int i = 0; i < 16; ++i)
        tile[tr + i * 4][tc] = in[(size_t)(r0 + tr + i * 4) * C + c0 + tc];
    __syncthreads();
    #pragma unroll
    for (int i = 0; i < 16; ++i)
        out[(size_t)(c0 + tr + i * 4) * R + r0 + tc] = (f16)tile[tc][tr + i * 4];
}

// fused fp32->f16 casts: z=0: x (8192 blocks), z=1..3: wq/wk/wv (1024 each)
__global__ __launch_bounds__(256)
void cast_all(const float* __restrict__ x, const float* __restrict__ wq,
              const float* __restrict__ wk, const float* __restrict__ wv,
              f16* __restrict__ xh, f16* __restrict__ wqh,
              f16* __restrict__ wkh, f16* __restrict__ wvh)
{
    const int z = blockIdx.z;
    const float* in; f16* out; unsigned nblk;
    if (z == 0)      { in = x;  out = xh;  nblk = 8192; }
    else if (z == 1) { in = wq; out = wqh; nblk = 1024; }
    else if (z == 2) { in = wk; out = wkh; nblk = 1024; }
    else             { in = wv; out = wvh; nblk = 1024; }
    if (blockIdx.x >= nblk) return;
    const size_t i = ((size_t)blockIdx.x * 256 + threadIdx.x) * 4;
    float4 v = *(const float4*)(in + i);
    f16x4 o; o.x = (f16)v.x; o.y = (f16)v.y; o.z = (f16)v.z; o.w = (f16)v.w;
    *(f16x4*)(out + i) = o;
}

// in-place row softmax: reads fp32 row (2048), writes f16 probs into the
// first half of the same row (row pitch 4096 f16). Wave shuffle reduce.
__global__ __launch_bounds__(256)
void softmax_f16(float* __restrict__ S)
{
    __shared__ float redm[4], reds[4];
    float* p = S + (size_t)blockIdx.x * 2048;
    f16* q = (f16*)p;
    const int t = threadIdx.x;
    const int lane = t & 63, wid = t >> 6;

    float4 u0 = *(const float4*)(p + t * 4);
    float4 u1 = *(const float4*)(p + 1024 + t * 4);

    float m = fmaxf(fmaxf(fmaxf(u0.x, u0.y), fmaxf(u0.z, u0.w)),
                    fmaxf(fmaxf(u1.x, u1.y), fmaxf(u1.z, u1.w)));
    #pragma unroll
    for (int off = 32; off > 0; off >>= 1)
        m = fmaxf(m, __shfl_xor(m, off));
    if (lane == 0) redm[wid] = m;
    __syncthreads();
    const float rowmax = fmaxf(fmaxf(redm[0], redm[1]),
                               fmaxf(redm[2], redm[3]));

    u0.x = __expf(u0.x - rowmax); u0.y = __expf(u0.y - rowmax);
    u0.z = __expf(u0.z - rowmax); u0.w = __expf(u0.w - rowmax);
    u1.x = __expf(u1.x - rowmax); u1.y = __expf(u1.y - rowmax);
    u1.z = __expf(u1.z - rowmax); u1.w = __expf(u1.w - rowmax);

    float s = (u0.x + u0.y + u0.z + u0.w) + (u1.x + u1.y + u1.z + u1.w);
    #pragma unroll
    for (int off = 32; off > 0; off >>= 1)
        s += __shfl_xor(s, off);
    if (lane == 0) reds[wid] = s;
    __syncthreads();   // also orders all row loads before the in-place write
    const float inv = 1.0f / (reds[0] + reds[1] + reds[2] + reds[3]);

    f16x4 o0, o1;
    o0.x = (f16)(u0.x * inv); o0.y = (f16)(u0.y * inv);
    o0.z = (f16)(u0.z * inv); o0.w = (f16)(u0.w * inv);
    o1.x = (f16)(u1.x * inv); o1.y = (f16)(u1.y * inv);
    o1.z = (f16)(u1.z * inv); o1.w = (f16)(u1.w * inv);
    *(f16x4*)(q + t * 4)        = o0;
    *(f16x4*)(q + 1024 + t * 4) = o1;
}

extern "C" void kernel_launch(void* const* d_in, const int* in_sizes, int n_in,
                              void* d_out, int out_size, void* d_ws, size_t ws_size,
                              hipStream_t stream)
{
    const float* x  = (const float*)d_in[0];
    const float* wq = (const float*)d_in[1];
    const float* wk = (const float*)d_in[2];
    const float* wv = (const float*)d_in[3];
    const float* wo = (const float*)d_in[4];
    const float* w1 = (const float*)d_in[5];
    const float* w2 = (const float*)d_in[6];
    float* out = (float*)d_out;

    const int S = 2048, D = 1024, DFF = 4096, Bb = 4;
    const int NTOK = Bb * S;  // 8192
    const size_t M1 = 1024 * 1024;

    // workspace (f16 units); peak 70M f16 = 140 MB (proven footprint).
    // Live-range map (NO overlaps among concurrently-live buffers):
    //   xh   0..8M    (live until FFN2 residual)
    //   weights 8..22M (wqh..w2T, wqkT, wvoT)
    //   qp   22..30M  (dead after scores) -> pj reuses this slot
    //   vwT  30..38M  (dead after PV)
    //   sb   38..70M  (fp32 scores 64MB; dead after PV) -> hd reuses
    f16* W    = (f16*)d_ws;
    f16* xh   = W;                      // [0, 8M)
    f16* wqh  = W + 8 * M1;             // 1M each
    f16* wkh  = W + 9 * M1;
    f16* wvh  = W + 10 * M1;
    f16* woT  = W + 11 * M1;
    f16* w1T  = W + 12 * M1;            // 4M
    f16* w2T  = W + 16 * M1;            // 4M
    f16* wqkT = W + 20 * M1;            // 1M  (= wk @ wq^T)
    f16* wvoT = W + 21 * M1;            // 1M  (= (wv @ wo)^T)
    f16* qp   = W + 22 * M1;            // 8M  (q' = x @ Wqk)
    f16* vwT  = W + 30 * M1;            // 8M  ([1024][8192] = (x @ Wvo)^T)
    float* sb = (float*)(W + 38 * M1);  // 32M f16 region = 64 MB fp32 scores
    f16* ph   = (f16*)sb;               // probs in-place, row pitch 4096 f16
    f16* pj   = qp;                     // PV out reuses qp (dead after scores)
    f16* hd   = W + 38 * M1;            // hidden reuses sb region (dead)

    dim3 blk(256);

    // fused casts / transposes, then weight products
    cast_all<<<dim3(NTOK * D / 1024, 1, 4), blk, 0, stream>>>(
        x, wq, wk, wv, xh, wqh, wkh, wvh);
    transpose_all<<<dim3(64, 64, 3), blk, 0, stream>>>(
        wo, w1, w2, woT, w1T, w2T);
    // wqkT = wk @ wq^T ; wvoT = NT(woT, wvh) = (wv @ wo)^T
    gemm_dd<<<dim3(16, 16, 2), blk, 0, stream>>>(
        wkh, wqh, wqkT, woT, wvh, wvoT);

    // qp = xh @ wqkT'  and  vwT = wvoT @ xh'  (merged, z role-swap)
    gemm_qv<<<dim3(NTOK / BM, D / BN, 2), blk, 0, stream>>>(
        xh, wqkT, wvoT, qp, vwT);

    // scores[b] = q'_b @ xh_b'   fp32 [2048][2048] x4
    gemm_ns2<2><<<dim3(S / BM, S / BN, Bb), blk, 0, stream>>>(
        qp, xh, sb, D, D, D, S,
        (long long)S * D, (long long)S * D, (long long)S * S);

    // softmax -> f16 probs in place (row pitch 4096)
    softmax_f16<<<dim3(NTOK), blk, 0, stream>>>(sb);

    // pj[b] = P_b @ (vwT[:, b-slice])'   [2048][1024] x4  (pj = qp slot)
    gemm_ns2<0><<<dim3(S / BM, D / BN, Bb), blk, 0, stream>>>(
        ph, vwT, pj, S, 4096, NTOK, D,
        (long long)S * 4096, (long long)S, (long long)S * D);

    // hidden = relu(pj @ w1T')   [8192][4096]  (hd = sb slot, sb dead)
    gemm_ns2<1><<<dim3(NTOK / BM, DFF / BN, 1), blk, 0, stream>>>(
        pj, w1T, hd, D, D, D, DFF, 0, 0, 0);

    // out = hd @ w2T' + xh (f16 residual)   fp32 [8192][1024]
    gemm_f16<3><<<dim3(NTOK / BM, D / BN, 1), blk, 0, stream>>>(
        hd, w2T, xh, out, DFF, DFF, DFF, D);
}

// Round 8
// 408.321 us; speedup vs baseline: 1.0420x; 1.0077x over previous
//
#include <hip/hip_runtime.h>
#include <hip/hip_bf16.h>
#include <hip/hip_fp16.h>

// TinyTransformerBlock: B=4, S=2048, D=1024, DFF=4096, fp32 in/out.
// R8: algebraic FLOP removal (245 GF). R10 8-phase FAILED; R11 XCD swizzle
// FAILED; R13 reg-diet neutral; R14 had a workspace aliasing bug; R15 fixed
// it and landed 411.5 us (best). R16 = confirmation resubmit of R15.
// Map: xh 0..8M | weights 8..22M | qp 22..30M | vwT 30..38M | sb 38..70M
//   pj = qp slot (dead after scores) | hd = sb slot (dead after PV)
// Peak 70M f16 = 140 MB. xh stays live as FFN2's f16 residual.
// Session plateau: 2-barrier 128^2 structure at its ~990 TF ceiling; all
// documented grafts null; deeper pipeline (m201-class) not reproducible
// from spec in this session (R10: correct but 36% MfmaUtil).

typedef _Float16 f16;
typedef __attribute__((ext_vector_type(8))) _Float16 f16x8;
typedef __attribute__((ext_vector_type(4))) _Float16 f16x4;
typedef __attribute__((ext_vector_type(4))) float f32x4;

#define BM 128
#define BN 128
#define BK 64

__device__ inline void gload16(const void* g, void* l) {
    __builtin_amdgcn_global_load_lds(
        (const __attribute__((address_space(1))) void*)g,
        (__attribute__((address_space(3))) void*)l, 16, 0, 0);
}

// ---------------- K-split kernel (128x128) — FFN2 (K=4096) ----------------
// EPI 3 = f32 store + f16 residual add. 8 acc tiles, 2-way wave K-split,
// LDS cross-reduce. Best measured for K=4096 (69.3 us R1).
template<int EPI>
__global__ __launch_bounds__(256, 2)
void gemm_f16(const f16* __restrict__ A, const f16* __restrict__ Bt,
              const f16* __restrict__ Res, float* __restrict__ C,
              int K, int lda, int ldb, int ldc)
{
    __shared__ char smem[32 * 1024];
    f16* Ash = (f16*)smem;
    f16* Bsh = (f16*)(smem + 16384);
    float* xbuf = (float*)smem;

    const int t = threadIdx.x;
    const int bm0 = blockIdx.x * BM;
    const int bn0 = blockIdx.y * BN;

    const int lane = t & 63;
    const int wid  = t >> 6;
    const int quad = lane >> 4;
    const int m16  = lane & 15;
    const int ks   = wid & 1;
    const int wn64 = (wid >> 1) * 64;

    const int r0 = t >> 3;
    const int kc = ((t & 7) ^ (r0 & 7)) * 8;
    const char* gA[4]; const char* gB[4];
    #pragma unroll
    for (int i = 0; i < 4; ++i) {
        gA[i] = (const char*)(A  + (size_t)(bm0 + i * 32 + r0) * lda + kc);
        gB[i] = (const char*)(Bt + (size_t)(bn0 + i * 32 + r0) * ldb + kc);
    }
    char* lA = (char*)Ash + (wid << 10);
    char* lB = (char*)Bsh + (wid << 10);

    f32x4 acc[8][4] = {};

    const int nk = K / BK;
    #define ISSUE(kt) do { const int ko = (kt) * 128;   \
        gload16(gA[0] + ko, lA);                        \
        gload16(gA[1] + ko, lA + 4096);                 \
        gload16(gA[2] + ko, lA + 8192);                 \
        gload16(gA[3] + ko, lA + 12288);                \
        gload16(gB[0] + ko, lB);                        \
        gload16(gB[1] + ko, lB + 4096);                 \
        gload16(gB[2] + ko, lB + 8192);                 \
        gload16(gB[3] + ko, lB + 12288); } while (0)

    const int swz = m16 & 7;
    const int ha  = ((ks * 4 + quad) ^ swz) * 8;

    ISSUE(0);
    for (int kt = 0; kt < nk; ++kt) {
        __syncthreads();
        f16x8 af[8], bf[4];
        #pragma unroll
        for (int i = 0; i < 8; ++i)
            af[i] = *(const f16x8*)&Ash[(i * 16 + m16) * BK + ha];
        #pragma unroll
        for (int j = 0; j < 4; ++j)
            bf[j] = *(const f16x8*)&Bsh[(wn64 + j * 16 + m16) * BK + ha];
        __syncthreads();
        if (kt + 1 < nk) ISSUE(kt + 1);
        #pragma unroll
        for (int i = 0; i < 8; ++i)
            #pragma unroll
            for (int j = 0; j < 4; ++j)
                acc[i][j] = __builtin_amdgcn_mfma_f32_16x16x32_f16(
                                af[i], bf[j], acc[i][j], 0, 0, 0);
    }
    #undef ISSUE

    float* xb = xbuf + (wid >> 1) * 4096;
    #define XIDX(row, col) ((row) * 64 + ((col) ^ (((row) & 4) << 2)))
    if (ks == 1) {
        #pragma unroll
        for (int i = 0; i < 4; ++i)
            #pragma unroll
            for (int j = 0; j < 4; ++j)
                #pragma unroll
                for (int ri = 0; ri < 4; ++ri)
                    xb[XIDX(i * 16 + quad * 4 + ri, j * 16 + m16)] = acc[i][j][ri];
    }
    __syncthreads();
    if (ks == 0) {
        #pragma unroll
        for (int i = 0; i < 4; ++i)
            #pragma unroll
            for (int j = 0; j < 4; ++j)
                #pragma unroll
                for (int ri = 0; ri < 4; ++ri)
                    acc[i][j][ri] += xb[XIDX(i * 16 + quad * 4 + ri, j * 16 + m16)];
    }
    __syncthreads();
    if (ks == 0) {
        #pragma unroll
        for (int i = 0; i < 4; ++i)
            #pragma unroll
            for (int j = 0; j < 4; ++j)
                #pragma unroll
                for (int ri = 0; ri < 4; ++ri)
                    xb[XIDX(i * 16 + quad * 4 + ri, j * 16 + m16)] = acc[i + 4][j][ri];
    }
    __syncthreads();
    if (ks == 1) {
        #pragma unroll
        for (int i = 0; i < 4; ++i)
            #pragma unroll
            for (int j = 0; j < 4; ++j)
                #pragma unroll
                for (int ri = 0; ri < 4; ++ri)
                    acc[i + 4][j][ri] += xb[XIDX(i * 16 + quad * 4 + ri, j * 16 + m16)];
    }
    #undef XIDX

    #define STORE_TILE(IB, RB)                                                  \
        do {                                                                    \
            _Pragma("unroll")                                                   \
            for (int i = 0; i < 4; ++i)                                         \
                _Pragma("unroll")                                               \
                for (int ri = 0; ri < 4; ++ri) {                                \
                    const size_t row = (size_t)(bm0 + (RB) + i * 16 + quad * 4 + ri); \
                    float* cp = C + row * ldc + (bn0 + wn64 + m16);             \
                    const f16* rp = Res + row * ldc + (bn0 + wn64 + m16);       \
                    _Pragma("unroll")                                           \
                    for (int j = 0; j < 4; ++j) {                               \
                        float v = acc[(IB) + i][j][ri];                         \
                        if (EPI == 3) v += (float)rp[j * 16];                   \
                        cp[j * 16] = v;                                         \
                    }                                                           \
                }                                                               \
        } while (0)

    if (ks == 0) STORE_TILE(0, 0);
    else         STORE_TILE(4, 64);
    #undef STORE_TILE
}

// ---------------- no-split kernel (128x128, wave=64x64, z-batch) ----------
// EPI: 0 = f16 store, 1 = f16 relu store, 2 = f32 store.  (R12 form.)
template<int EPI>
__global__ __launch_bounds__(256, 2)
void gemm_ns2(const f16* __restrict__ A, const f16* __restrict__ Bt,
              void* __restrict__ Cv,
              int K, int lda, int ldb, int ldc,
              long long sA, long long sB, long long sC)
{
    __shared__ f16 Ash[BM * BK];
    __shared__ f16 Bsh[BN * BK];

    const int t = threadIdx.x;
    const int z = blockIdx.z;
    A  += (size_t)z * sA;
    Bt += (size_t)z * sB;

    const int bm0 = blockIdx.x * BM;
    const int bn0 = blockIdx.y * BN;

    const int lane = t & 63;
    const int wid  = t >> 6;
    const int quad = lane >> 4;
    const int m16  = lane & 15;
    const int wm = (wid & 1) * 64;
    const int wn = (wid >> 1) * 64;

    const int r0 = t >> 3;
    const int kc = ((t & 7) ^ (r0 & 7)) * 8;
    const char* gA[4]; const char* gB[4];
    #pragma unroll
    for (int i = 0; i < 4; ++i) {
        gA[i] = (const char*)(A  + (size_t)(bm0 + i * 32 + r0) * lda + kc);
        gB[i] = (const char*)(Bt + (size_t)(bn0 + i * 32 + r0) * ldb + kc);
    }
    char* lA = (char*)Ash + (wid << 10);
    char* lB = (char*)Bsh + (wid << 10);

    f32x4 acc[4][4] = {};

    const int nk = K / BK;
    #define ISSUE(kt) do { const int ko = (kt) * 128;   \
        gload16(gA[0] + ko, lA);                        \
        gload16(gA[1] + ko, lA + 4096);                 \
        gload16(gA[2] + ko, lA + 8192);                 \
        gload16(gA[3] + ko, lA + 12288);                \
        gload16(gB[0] + ko, lB);                        \
        gload16(gB[1] + ko, lB + 4096);                 \
        gload16(gB[2] + ko, lB + 8192);                 \
        gload16(gB[3] + ko, lB + 12288); } while (0)

    const int swz = m16 & 7;

    ISSUE(0);
    for (int kt = 0; kt < nk; ++kt) {
        __syncthreads();
        f16x8 af[2][4], bf[2][4];
        #pragma unroll
        for (int s = 0; s < 2; ++s) {
            const int ha = (((s << 2) | quad) ^ swz) * 8;
            #pragma unroll
            for (int i = 0; i < 4; ++i) {
                af[s][i] = *(const f16x8*)&Ash[(wm + i * 16 + m16) * BK + ha];
                bf[s][i] = *(const f16x8*)&Bsh[(wn + i * 16 + m16) * BK + ha];
            }
        }
        __syncthreads();
        if (kt + 1 < nk) ISSUE(kt + 1);
        #pragma unroll
        for (int s = 0; s < 2; ++s)
            #pragma unroll
            for (int i = 0; i < 4; ++i)
                #pragma unroll
                for (int j = 0; j < 4; ++j)
                    acc[i][j] = __builtin_amdgcn_mfma_f32_16x16x32_f16(
                                    af[s][i], bf[s][j], acc[i][j], 0, 0, 0);
    }
    #undef ISSUE

    if (EPI <= 1) {
        f16* C = (f16*)Cv + (size_t)z * sC;
        #pragma unroll
        for (int i = 0; i < 4; ++i)
            #pragma unroll
            for (int ri = 0; ri < 4; ++ri) {
                const size_t row = (size_t)(bm0 + wm + i * 16 + quad * 4 + ri);
                f16* cp = C + row * ldc + (bn0 + wn + m16);
                #pragma unroll
                for (int j = 0; j < 4; ++j) {
                    float v = acc[i][j][ri];
                    if (EPI == 1) v = fmaxf(v, 0.0f);
                    cp[j * 16] = (f16)v;
                }
            }
    } else {
        float* C = (float*)Cv + (size_t)z * sC;
        #pragma unroll
        for (int i = 0; i < 4; ++i)
            #pragma unroll
            for (int ri = 0; ri < 4; ++ri) {
                const size_t row = (size_t)(bm0 + wm + i * 16 + quad * 4 + ri);
                float* cp = C + row * ldc + (bn0 + wn + m16);
                #pragma unroll
                for (int j = 0; j < 4; ++j)
                    cp[j * 16] = acc[i][j][ri];
            }
    }
}

// ---------------- merged qp + vwT launch (z role-swap, K=1024) ------------
// z=0: qp[8192][1024] = xh @ wqkT^T   (bx = M blocks 64, by = N blocks 8)
// z=1: vwT[1024][8192] = wvoT @ xh^T  (by = M blocks 8,  bx = N blocks 64)
__global__ __launch_bounds__(256, 2)
void gemm_qv(const f16* __restrict__ xh, const f16* __restrict__ wqkT,
             const f16* __restrict__ wvoT,
             f16* __restrict__ qp, f16* __restrict__ vwT)
{
    __shared__ f16 Ash[BM * BK];
    __shared__ f16 Bsh[BN * BK];

    const int t = threadIdx.x;
    const int z = blockIdx.z;
    const f16* A  = z ? wvoT : xh;
    const f16* Bt = z ? xh   : wqkT;
    f16* C        = z ? vwT  : qp;
    const int lda = 1024, ldb = 1024;
    const int ldc = z ? 8192 : 1024;
    const int bm0 = (z ? blockIdx.y : blockIdx.x) * BM;
    const int bn0 = (z ? blockIdx.x : blockIdx.y) * BN;

    const int lane = t & 63;
    const int wid  = t >> 6;
    const int quad = lane >> 4;
    const int m16  = lane & 15;
    const int wm = (wid & 1) * 64;
    const int wn = (wid >> 1) * 64;

    const int r0 = t >> 3;
    const int kc = ((t & 7) ^ (r0 & 7)) * 8;
    const char* gA[4]; const char* gB[4];
    #pragma unroll
    for (int i = 0; i < 4; ++i) {
        gA[i] = (const char*)(A  + (size_t)(bm0 + i * 32 + r0) * lda + kc);
        gB[i] = (const char*)(Bt + (size_t)(bn0 + i * 32 + r0) * ldb + kc);
    }
    char* lA = (char*)Ash + (wid << 10);
    char* lB = (char*)Bsh + (wid << 10);

    f32x4 acc[4][4] = {};

    #define ISSUE(kt) do { const int ko = (kt) * 128;   \
        gload16(gA[0] + ko, lA);                        \
        gload16(gA[1] + ko, lA + 4096);                 \
        gload16(gA[2] + ko, lA + 8192);                 \
        gload16(gA[3] + ko, lA + 12288);                \
        gload16(gB[0] + ko, lB);                        \
        gload16(gB[1] + ko, lB + 4096);                 \
        gload16(gB[2] + ko, lB + 8192);                 \
        gload16(gB[3] + ko, lB + 12288); } while (0)

    const int swz = m16 & 7;

    ISSUE(0);
    for (int kt = 0; kt < 16; ++kt) {    // K = 1024
        __syncthreads();
        f16x8 af[2][4], bf[2][4];
        #pragma unroll
        for (int s = 0; s < 2; ++s) {
            const int ha = (((s << 2) | quad) ^ swz) * 8;
            #pragma unroll
            for (int i = 0; i < 4; ++i) {
                af[s][i] = *(const f16x8*)&Ash[(wm + i * 16 + m16) * BK + ha];
                bf[s][i] = *(const f16x8*)&Bsh[(wn + i * 16 + m16) * BK + ha];
            }
        }
        __syncthreads();
        if (kt + 1 < 16) ISSUE(kt + 1);
        #pragma unroll
        for (int s = 0; s < 2; ++s)
            #pragma unroll
            for (int i = 0; i < 4; ++i)
                #pragma unroll
                for (int j = 0; j < 4; ++j)
                    acc[i][j] = __builtin_amdgcn_mfma_f32_16x16x32_f16(
                                    af[s][i], bf[s][j], acc[i][j], 0, 0, 0);
    }
    #undef ISSUE

    #pragma unroll
    for (int i = 0; i < 4; ++i)
        #pragma unroll
        for (int ri = 0; ri < 4; ++ri) {
            const size_t row = (size_t)(bm0 + wm + i * 16 + quad * 4 + ri);
            f16* cp = C + row * ldc + (bn0 + wn + m16);
            #pragma unroll
            for (int j = 0; j < 4; ++j)
                cp[j * 16] = (f16)acc[i][j][ri];
        }
}

// ---------------- small D x D kernel: two 1024^3 products in one launch ---
__global__ __launch_bounds__(256, 2)
void gemm_dd(const f16* __restrict__ A0, const f16* __restrict__ B0, f16* __restrict__ C0,
             const f16* __restrict__ A1, const f16* __restrict__ B1, f16* __restrict__ C1)
{
    const int LD = 1024;
    __shared__ char smem[32 * 1024];
    f16* Ash = (f16*)smem;             // 16 KB: 64 rows x 128 k
    f16* Bsh = (f16*)(smem + 16384);   // 16 KB
    float* xred = (float*)smem;        // reduce regions alias staging

    const int t = threadIdx.x;
    const int z = blockIdx.z;
    const f16* A = z ? A1 : A0;
    const f16* B = z ? B1 : B0;
    f16* C = z ? C1 : C0;

    const int bm0 = blockIdx.x * 64;
    const int bn0 = blockIdx.y * 64;

    const int lane = t & 63;
    const int wid  = t >> 6;            // wave = k-quarter ks
    const int quad = lane >> 4;
    const int m16  = lane & 15;

    const int rr = t >> 4;              // 0..15
    const int kc = ((t & 15) ^ (rr & 15)) * 8;
    const char* gA[4]; const char* gB[4];
    #pragma unroll
    for (int i = 0; i < 4; ++i) {
        gA[i] = (const char*)(A + (size_t)(bm0 + i * 16 + rr) * LD + kc);
        gB[i] = (const char*)(B + (size_t)(bn0 + i * 16 + rr) * LD + kc);
    }
    char* lA = (char*)Ash + (wid << 10);
    char* lB = (char*)Bsh + (wid << 10);

    f32x4 acc[4][4] = {};

    #define ISSUE(kt) do { const int ko = (kt) * 256;   \
        gload16(gA[0] + ko, lA);                        \
        gload16(gA[1] + ko, lA + 4096);                 \
        gload16(gA[2] + ko, lA + 8192);                 \
        gload16(gA[3] + ko, lA + 12288);                \
        gload16(gB[0] + ko, lB);                        \
        gload16(gB[1] + ko, lB + 4096);                 \
        gload16(gB[2] + ko, lB + 8192);                 \
        gload16(gB[3] + ko, lB + 12288); } while (0)

    const int sl = ((wid * 4 + quad) ^ m16) * 8;   // swizzled slot (16 slots)

    ISSUE(0);
    for (int kt = 0; kt < 8; ++kt) {     // K = 1024, BK = 128
        __syncthreads();
        f16x8 af[4], bf[4];
        #pragma unroll
        for (int i = 0; i < 4; ++i) {
            af[i] = *(const f16x8*)&Ash[(i * 16 + m16) * 128 + sl];
            bf[i] = *(const f16x8*)&Bsh[(i * 16 + m16) * 128 + sl];
        }
        __syncthreads();
        if (kt + 1 < 8) ISSUE(kt + 1);
        #pragma unroll
        for (int i = 0; i < 4; ++i)
            #pragma unroll
            for (int j = 0; j < 4; ++j)
                acc[i][j] = __builtin_amdgcn_mfma_f32_16x16x32_f16(
                                af[i], bf[j], acc[i][j], 0, 0, 0);
    }
    #undef ISSUE

    #define XIDX(row, col) ((row) * 64 + ((col) ^ (((row) & 4) << 2)))
    #define WR(base) do {                                                       \
        _Pragma("unroll")                                                       \
        for (int i = 0; i < 4; ++i)                                             \
            _Pragma("unroll")                                                   \
            for (int j = 0; j < 4; ++j)                                         \
                _Pragma("unroll")                                               \
                for (int ri = 0; ri < 4; ++ri)                                  \
                    (base)[XIDX(i * 16 + quad * 4 + ri, j * 16 + m16)] = acc[i][j][ri]; \
        } while (0)
    #define RD(base) do {                                                       \
        _Pragma("unroll")                                                       \
        for (int i = 0; i < 4; ++i)                                             \
            _Pragma("unroll")                                                   \
            for (int j = 0; j < 4; ++j)                                         \
                _Pragma("unroll")                                               \
                for (int ri = 0; ri < 4; ++ri)                                  \
                    acc[i][j][ri] += (base)[XIDX(i * 16 + quad * 4 + ri, j * 16 + m16)]; \
        } while (0)

    __syncthreads();
    if (wid == 2) WR(xred);
    if (wid == 3) WR(xred + 4096);
    __syncthreads();
    if (wid == 0) RD(xred);
    if (wid == 1) RD(xred + 4096);
    __syncthreads();
    if (wid == 1) WR(xred);
    __syncthreads();
    if (wid == 0) {
        RD(xred);
        #pragma unroll
        for (int i = 0; i < 4; ++i)
            #pragma unroll
            for (int ri = 0; ri < 4; ++ri) {
                const size_t row = (size_t)(bm0 + i * 16 + quad * 4 + ri);
                f16* cp = C + row * LD + (bn0 + m16);
                #pragma unroll
                for (int j = 0; j < 4; ++j)
                    cp[j * 16] = (f16)acc[i][j][ri];
            }
    }
    #undef WR
    #undef RD
    #undef XIDX
}

// fused fp32 [R][C] -> fp16 [C][R] for wo/w1/w2 in one launch (z = 0..2)
__global__ __launch_bounds__(256)
void transpose_all(const float* __restrict__ wo, const float* __restrict__ w1,
                   const float* __restrict__ w2,
                   f16* __restrict__ woT, f16* __restrict__ w1T,
                   f16* __restrict__ w2T)
{
    const int z = blockIdx.z;
    const float* in; f16* out; int R, C, gx, gy;
    if (z == 0)      { in = wo; out = woT; R = 1024; C = 1024; gx = 16; gy = 16; }
    else if (z == 1) { in = w1; out = w1T; R = 1024; C = 4096; gx = 64; gy = 16; }
    else             { in = w2; out = w2T; R = 4096; C = 1024; gx = 16; gy = 64; }
    if (blockIdx.x >= (unsigned)gx || blockIdx.y >= (unsigned)gy) return;

    __shared__ float tile[64][65];
    const int c0 = blockIdx.x * 64, r0 = blockIdx.y * 64;
    const int tc = threadIdx.x & 63, tr = threadIdx.x >> 6;
    #pragma unroll
    for (int i = 0; i < 16; ++i)
        tile[tr + i * 4][tc] = in[(size_t)(r0 + tr + i * 4) * C + c0 + tc];
    __syncthreads();
    #pragma unroll
    for (int i = 0; i < 16; ++i)
        out[(size_t)(c0 + tr + i * 4) * R + r0 + tc] = (f16)tile[tc][tr + i * 4];
}

// fused fp32->f16 casts: z=0: x (8192 blocks), z=1..3: wq/wk/wv (1024 each)
__global__ __launch_bounds__(256)
void cast_all(const float* __restrict__ x, const float* __restrict__ wq,
              const float* __restrict__ wk, const float* __restrict__ wv,
              f16* __restrict__ xh, f16* __restrict__ wqh,
              f16* __restrict__ wkh, f16* __restrict__ wvh)
{
    const int z = blockIdx.z;
    const float* in; f16* out; unsigned nblk;
    if (z == 0)      { in = x;  out = xh;  nblk = 8192; }
    else if (z == 1) { in = wq; out = wqh; nblk = 1024; }
    else if (z == 2) { in = wk; out = wkh; nblk = 1024; }
    else             { in = wv; out = wvh; nblk = 1024; }
    if (blockIdx.x >= nblk) return;
    const size_t i = ((size_t)blockIdx.x * 256 + threadIdx.x) * 4;
    float4 v = *(const float4*)(in + i);
    f16x4 o; o.x = (f16)v.x; o.y = (f16)v.y; o.z = (f16)v.z; o.w = (f16)v.w;
    *(f16x4*)(out + i) = o;
}

// in-place row softmax: reads fp32 row (2048), writes f16 probs into the
// first half of the same row (row pitch 4096 f16). Wave shuffle reduce.
__global__ __launch_bounds__(256)
void softmax_f16(float* __restrict__ S)
{
    __shared__ float redm[4], reds[4];
    float* p = S + (size_t)blockIdx.x * 2048;
    f16* q = (f16*)p;
    const int t = threadIdx.x;
    const int lane = t & 63, wid = t >> 6;

    float4 u0 = *(const float4*)(p + t * 4);
    float4 u1 = *(const float4*)(p + 1024 + t * 4);

    float m = fmaxf(fmaxf(fmaxf(u0.x, u0.y), fmaxf(u0.z, u0.w)),
                    fmaxf(fmaxf(u1.x, u1.y), fmaxf(u1.z, u1.w)));
    #pragma unroll
    for (int off = 32; off > 0; off >>= 1)
        m = fmaxf(m, __shfl_xor(m, off));
    if (lane == 0) redm[wid] = m;
    __syncthreads();
    const float rowmax = fmaxf(fmaxf(redm[0], redm[1]),
                               fmaxf(redm[2], redm[3]));

    u0.x = __expf(u0.x - rowmax); u0.y = __expf(u0.y - rowmax);
    u0.z = __expf(u0.z - rowmax); u0.w = __expf(u0.w - rowmax);
    u1.x = __expf(u1.x - rowmax); u1.y = __expf(u1.y - rowmax);
    u1.z = __expf(u1.z - rowmax); u1.w = __expf(u1.w - rowmax);

    float s = (u0.x + u0.y + u0.z + u0.w) + (u1.x + u1.y + u1.z + u1.w);
    #pragma unroll
    for (int off = 32; off > 0; off >>= 1)
        s += __shfl_xor(s, off);
    if (lane == 0) reds[wid] = s;
    __syncthreads();   // also orders all row loads before the in-place write
    const float inv = 1.0f / (reds[0] + reds[1] + reds[2] + reds[3]);

    f16x4 o0, o1;
    o0.x = (f16)(u0.x * inv); o0.y = (f16)(u0.y * inv);
    o0.z = (f16)(u0.z * inv); o0.w = (f16)(u0.w * inv);
    o1.x = (f16)(u1.x * inv); o1.y = (f16)(u1.y * inv);
    o1.z = (f16)(u1.z * inv); o1.w = (f16)(u1.w * inv);
    *(f16x4*)(q + t * 4)        = o0;
    *(f16x4*)(q + 1024 + t * 4) = o1;
}

extern "C" void kernel_launch(void* const* d_in, const int* in_sizes, int n_in,
                              void* d_out, int out_size, void* d_ws, size_t ws_size,
                              hipStream_t stream)
{
    const float* x  = (const float*)d_in[0];
    const float* wq = (const float*)d_in[1];
    const float* wk = (const float*)d_in[2];
    const float* wv = (const float*)d_in[3];
    const float* wo = (const float*)d_in[4];
    const float* w1 = (const float*)d_in[5];
    const float* w2 = (const float*)d_in[6];
    float* out = (float*)d_out;

    const int S = 2048, D = 1024, DFF = 4096, Bb = 4;
    const int NTOK = Bb * S;  // 8192
    const size_t M1 = 1024 * 1024;

    // workspace (f16 units); peak 70M f16 = 140 MB (proven footprint).
    // Live-range map (NO overlaps among concurrently-live buffers):
    //   xh   0..8M    (live until FFN2 residual)
    //   weights 8..22M (wqh..w2T, wqkT, wvoT)
    //   qp   22..30M  (dead after scores) -> pj reuses this slot
    //   vwT  30..38M  (dead after PV)
    //   sb   38..70M  (fp32 scores 64MB; dead after PV) -> hd reuses
    f16* W    = (f16*)d_ws;
    f16* xh   = W;                      // [0, 8M)
    f16* wqh  = W + 8 * M1;             // 1M each
    f16* wkh  = W + 9 * M1;
    f16* wvh  = W + 10 * M1;
    f16* woT  = W + 11 * M1;
    f16* w1T  = W + 12 * M1;            // 4M
    f16* w2T  = W + 16 * M1;            // 4M
    f16* wqkT = W + 20 * M1;            // 1M  (= wk @ wq^T)
    f16* wvoT = W + 21 * M1;            // 1M  (= (wv @ wo)^T)
    f16* qp   = W + 22 * M1;            // 8M  (q' = x @ Wqk)
    f16* vwT  = W + 30 * M1;            // 8M  ([1024][8192] = (x @ Wvo)^T)
    float* sb = (float*)(W + 38 * M1);  // 32M f16 region = 64 MB fp32 scores
    f16* ph   = (f16*)sb;               // probs in-place, row pitch 4096 f16
    f16* pj   = qp;                     // PV out reuses qp (dead after scores)
    f16* hd   = W + 38 * M1;            // hidden reuses sb region (dead)

    dim3 blk(256);

    // fused casts / transposes, then weight products
    cast_all<<<dim3(NTOK * D / 1024, 1, 4), blk, 0, stream>>>(
        x, wq, wk, wv, xh, wqh, wkh, wvh);
    transpose_all<<<dim3(64, 64, 3), blk, 0, stream>>>(
        wo, w1, w2, woT, w1T, w2T);
    // wqkT = wk @ wq^T ; wvoT = NT(woT, wvh) = (wv @ wo)^T
    gemm_dd<<<dim3(16, 16, 2), blk, 0, stream>>>(
        wkh, wqh, wqkT, woT, wvh, wvoT);

    // qp = xh @ wqkT'  and  vwT = wvoT @ xh'  (merged, z role-swap)
    gemm_qv<<<dim3(NTOK / BM, D / BN, 2), blk, 0, stream>>>(
        xh, wqkT, wvoT, qp, vwT);

    // scores[b] = q'_b @ xh_b'   fp32 [2048][2048] x4
    gemm_ns2<2><<<dim3(S / BM, S / BN, Bb), blk, 0, stream>>>(
        qp, xh, sb, D, D, D, S,
        (long long)S * D, (long long)S * D, (long long)S * S);

    // softmax -> f16 probs in place (row pitch 4096)
    softmax_f16<<<dim3(NTOK), blk, 0, stream>>>(sb);

    // pj[b] = P_b @ (vwT[:, b-slice])'   [2048][1024] x4  (pj = qp slot)
    gemm_ns2<0><<<dim3(S / BM, D / BN, Bb), blk, 0, stream>>>(
        ph, vwT, pj, S, 4096, NTOK, D,
        (long long)S * 4096, (long long)S, (long long)S * D);

    // hidden = relu(pj @ w1T')   [8192][4096]  (hd = sb slot, sb dead)
    gemm_ns2<1><<<dim3(NTOK / BM, DFF / BN, 1), blk, 0, stream>>>(
        pj, w1T, hd, D, D, D, DFF, 0, 0, 0);

    // out = hd @ w2T' + xh (f16 residual)   fp32 [8192][1024]
    gemm_f16<3><<<dim3(NTOK / BM, D / BN, 1), blk, 0, stream>>>(
        hd, w2T, xh, out, DFF, DFF, DFF, D);
}